// Round 12
// baseline (16.879 us; speedup 1.0000x reference)
//
#include <hip/hip_runtime.h>

// Warp_Object bicubic warp: B=4, C=3, H=512, W=512, float32.
// Round 12: counted-vmcnt phase pipeline (T3/T4 port). r11 drained vmcnt(0)
// for ALL 3 planes' staging before any stencil -> HBM burst serialized with
// compute. Now: per-wave UNIFORM staging (2 gload_lds per plane per wave,
// 85 chunks/wave/plane, 2nd instr partial-exec) lets every wave use the same
// compile-time vmcnt literal. Per plane: s_waitcnt vmcnt(4) + raw s_barrier
// -> stencil + stores. Each wait leaves later planes' loads in flight, so
// staging(c+1) overlaps stencil(c). Geometry identical to r11.

constexpr int B = 4, C = 3, H = 512, W = 512;
constexpr int HW = H * W;              // 2^18
constexpr int TH = 8;                  // output rows per block
constexpr int HALO_UP = 6, HALO_DN = 6;
constexpr int RS = TH + HALO_UP + HALO_DN;   // 20 staged rows
constexpr int LST = 272;               // staged cols; %32=16 bank rotate
constexpr int CH_ROW = LST / 4;        // 68 f4 chunks per staged row
constexpr int NCHUNK = RS * CH_ROW;    // 1360 chunks per plane
constexpr int CPW = NCHUNK / 16;       // 85 chunks per wave per plane
constexpr int TILE_DW = RS * LST;      // 5440 dwords per plane
constexpr int NPOS = 2;                // positions per thread
constexpr int NT = 1024;               // threads per block
constexpr int NB = B * (H / TH) * 2;   // 512 blocks

typedef float f4 __attribute__((ext_vector_type(4)));
typedef f4 f4u __attribute__((aligned(4)));   // 4B-aligned float4 load

typedef const __attribute__((address_space(1))) void* gas_t;
typedef __attribute__((address_space(3))) void* las_t;

__device__ __forceinline__ void gload_lds16(const float* g, float* l) {
    __builtin_amdgcn_global_load_lds((gas_t)g, (las_t)l, 16, 0, 0);
}

// counted wait: 4 vmem ops may stay in flight (later staging / prior stores)
#define PHASE_GATE() do {                                   \
    asm volatile("s_waitcnt vmcnt(4)" ::: "memory");        \
    __builtin_amdgcn_sched_barrier(0);                      \
    __builtin_amdgcn_s_barrier();                           \
    __builtin_amdgcn_sched_barrier(0);                      \
} while (0)

__global__ __launch_bounds__(NT, 8)
void warp_bicubic_pipe(const float* __restrict__ img,
                       const float* __restrict__ dxp,
                       const float* __restrict__ dyp,
                       float* __restrict__ out)
{
    __shared__ float tile[C][TILE_DW];         // 65,280 B -> 2 blocks/CU

    int b   = blockIdx.x;
    int swz = (b & 7) * (NB / 8) + (b >> 3);   // XCD-chunked, bijective (512=8*64)
    int bd   = swz >> 7;                       // displacement batch 0..3
    int band = (swz >> 1) & 63;
    int half = swz & 1;
    int yb   = band * TH;
    int xb   = half * 256;
    int cb   = half ? 248 : 0;                 // first staged image col

    int tid  = threadIdx.x;
    int wv   = tid >> 6;                       // wave 0..15
    int lane = tid & 63;
    int ry   = wv >> 1;                        // row in band 0..7
    int hw   = wv & 1;                         // 128-col subhalf
    int y    = yb + ry;
    int xs   = xb + hw * 128 + lane;           // x = xs + 64p, lanes consecutive
    int pixoff = y * W + xs;

    // ---- 1) dx/dy loads FIRST (their implicit wait must not drain staging)
    float dxa[NPOS], dya[NPOS];
#pragma unroll
    for (int p = 0; p < NPOS; ++p) {
        dxa[p] = __builtin_nontemporal_load(dxp + bd * HW + pixoff + 64 * p);
        dya[p] = __builtin_nontemporal_load(dyp + bd * HW + pixoff + 64 * p);
    }

    // ---- 2) staging: per-wave uniform 2 gload_lds per plane (6 total) ----
#pragma unroll
    for (int c = 0; c < C; ++c) {
        const float* plane = img + (size_t)(bd + 4 * c) * HW;
#pragma unroll
        for (int i = 0; i < 2; ++i) {
            int chunk = wv * CPW + i * 64 + lane;       // < 1360 when active
            if (i == 0 || lane < CPW - 64) {            // 2nd instr: 21 lanes
                int r  = chunk / CH_ROW;
                int c4 = (chunk - r * CH_ROW) * 4;
                int scol = min(cb + c4, W - 4);         // tail cols never read
                int sr   = min(max(yb - HALO_UP + r, 0), H - 1);
                gload_lds16(plane + sr * W + scol, &tile[c][chunk * 4]);
            }
        }
    }

    // ---- 3) coefficients (VALU overlaps staging flight; reused x3 planes)
    float wx[NPOS][4];      // x-weights (image-edge clamp folded)
    float cyw[NPOS][4];     // y-coefficients
    int   lbase[NPOS];
    unsigned relv[NPOS], lsv[NPOS];
    bool  intile[NPOS];
#pragma unroll
    for (int p = 0; p < NPOS; ++p) {
        int x = xs + 64 * p;
        float xm = (float)x + dxa[p];          // == ref up to ~3e-5 px rounding
        float ym = (float)y + dya[p];
        float x0f = floorf(xm), y0f = floorf(ym);
        float tx = xm - x0f, ty = ym - y0f;
        int x0 = (int)x0f, y0 = (int)y0f;
        int s  = min(max(x0 - 1, 0), W - 4);   // 4-wide window start (image cols)

        float tx2 = tx * tx, tx3 = tx2 * tx;
        float cx0 = (-tx3 + 2.0f * tx2 - tx) * 0.5f;
        float cx1 = (3.0f * tx3 - 5.0f * tx2 + 2.0f) * 0.5f;
        float cx2 = (-3.0f * tx3 + 4.0f * tx2 + tx) * 0.5f;
        float cx3 = 1.0f - (cx0 + cx1 + cx2);

        float ty2 = ty * ty, ty3 = ty2 * ty;
        cyw[p][0] = (-ty3 + 2.0f * ty2 - ty) * 0.5f;
        cyw[p][1] = (3.0f * ty3 - 5.0f * ty2 + 2.0f) * 0.5f;
        cyw[p][2] = (-3.0f * ty3 + 4.0f * ty2 + ty) * 0.5f;
        cyw[p][3] = 1.0f - (cyw[p][0] + cyw[p][1] + cyw[p][2]);

        if (__builtin_expect(x0 >= 1 && x0 <= W - 3, 1)) {
            wx[p][0] = cx0; wx[p][1] = cx1; wx[p][2] = cx2; wx[p][3] = cx3;
        } else {                               // fold image-edge taps into window
            float w0 = 0.f, w1 = 0.f, w2 = 0.f, w3 = 0.f;
            const float cxa[4] = {cx0, cx1, cx2, cx3};
#pragma unroll
            for (int o = 0; o < 4; ++o) {
                int xi = min(max(x0 - 1 + o, 0), W - 1);
                int e  = xi - s;               // 0..3 always
                float c = cxa[o];
                w0 += (e == 0) ? c : 0.f;
                w1 += (e == 1) ? c : 0.f;
                w2 += (e == 2) ? c : 0.f;
                w3 += (e == 3) ? c : 0.f;
            }
            wx[p][0] = w0; wx[p][1] = w1; wx[p][2] = w2; wx[p][3] = w3;
        }

        relv[p]  = (unsigned)(y0 - (yb - HALO_UP + 1));  // staged row of y0-1
        lsv[p]   = (unsigned)(s - cb);                   // staged col of window
        intile[p] = (relv[p] <= (unsigned)(RS - 4)) & (lsv[p] <= (unsigned)(LST - 4));
        lbase[p] = (int)relv[p] * LST + (int)lsv[p];
    }

    // ---- 4) per-plane: counted gate -> stencil -> NT stores ----
#pragma unroll
    for (int c = 0; c < C; ++c) {
        PHASE_GATE();   // own plane-c staging landed; later planes stay in flight

        int kp = bd + 4 * c;
        const float* __restrict__ plane = img + (size_t)kp * HW;
        const float* __restrict__ tp = &tile[c][0];
        float* __restrict__ obase = out + (size_t)kp * HW + pixoff;
#pragma unroll
        for (int p = 0; p < NPOS; ++p) {
            float acc;
            if (__builtin_expect(intile[p], 1)) {
                const float* rp = tp + lbase[p];
                float r0 = cyw[p][0] * (wx[p][0]*rp[0] + wx[p][1]*rp[1] + wx[p][2]*rp[2] + wx[p][3]*rp[3]);
                rp += LST;
                float r1 = cyw[p][1] * (wx[p][0]*rp[0] + wx[p][1]*rp[1] + wx[p][2]*rp[2] + wx[p][3]*rp[3]);
                rp += LST;
                float r2 = cyw[p][2] * (wx[p][0]*rp[0] + wx[p][1]*rp[1] + wx[p][2]*rp[2] + wx[p][3]*rp[3]);
                rp += LST;
                float r3 = cyw[p][3] * (wx[p][0]*rp[0] + wx[p][1]*rp[1] + wx[p][2]*rp[2] + wx[p][3]*rp[3]);
                acc = (r0 + r1) + (r2 + r3);
            } else {
                // rare Gaussian-tail escape: always-correct global path
                int y0 = (int)relv[p] + (yb - HALO_UP + 1);
                int s  = (int)lsv[p] + cb;
                acc = 0.f;
#pragma unroll
                for (int j = 0; j < 4; ++j) {
                    int yi = min(max(y0 - 1 + j, 0), H - 1);
                    f4 v = *(const f4u*)(plane + yi * W + s);
                    acc += cyw[p][j] * (wx[p][0]*v.x + wx[p][1]*v.y + wx[p][2]*v.z + wx[p][3]*v.w);
                }
            }
            __builtin_nontemporal_store(acc, obase + 64 * p);
        }
    }
}

extern "C" void kernel_launch(void* const* d_in, const int* in_sizes, int n_in,
                              void* d_out, int out_size, void* d_ws, size_t ws_size,
                              hipStream_t stream) {
    const float* img = (const float*)d_in[0];
    const float* dx  = (const float*)d_in[1];
    const float* dy  = (const float*)d_in[2];
    float* out = (float*)d_out;

    dim3 block(NT);
    dim3 grid(NB);   // 512 blocks -> 2 resident blocks/CU, whole grid co-resident
    hipLaunchKernelGGL(warp_bicubic_pipe, grid, block, 0, stream,
                       img, dx, dy, out);
}

// Round 13
// 16.046 us; speedup vs baseline: 1.0519x; 1.0519x over previous
//
#include <hip/hip_runtime.h>

// Warp_Object bicubic warp: B=4, C=3, H=512, W=512, float32.
// Round 13: break grid-wide phase lockstep. Since r8, 6 px/thread made the
// grid EXACTLY one resident generation (524K threads = 256CU x 2048): all
// blocks stage in one global HBM burst (paid as latency by every wave), then
// all stencil (HBM idle) -> phases serialize grid-wide; r9-r12's intra-block
// levers were all null. Now NPOS=1 (3 px/thread): 1024 blocks of 1024 thr,
// 512 resident -> 2 dispatch generations; gen-2 staging overlaps gen-1
// stencil via the dispatcher. Tile 32x32 (halo 6 -> 44x48 staged) also cuts
// img fetch amp 2.65x -> 2.06x. 1 gload_lds per wave per plane (33 lanes).
// cb=clamp(xb-6,0,464): all staged loads in-bounds, exact col map, edge
// tiles one-sided halo; escapes are Gaussian tails -> global fallback.

constexpr int B = 4, C = 3, H = 512, W = 512;
constexpr int HW = H * W;              // 2^18
constexpr int TH2 = 32, TW = 32;       // output tile
constexpr int HALO = 6;
constexpr int RS = TH2 + 2 * HALO;     // 44 staged rows
constexpr int LSTC = 48;               // staged cols (<=44 used + pad); %32=16
constexpr int CHR = LSTC / 4;          // 12 f4 chunks per staged row
constexpr int NCH = RS * CHR;          // 528 chunks per plane
constexpr int CPW = NCH / 16;          // 33 chunks per wave per plane
constexpr int TDW = RS * LSTC;         // 2112 dwords per plane
constexpr int NT = 1024;
constexpr int NB = B * (H / TH2) * (W / TW);   // 1024 blocks

typedef float f4 __attribute__((ext_vector_type(4)));
typedef f4 f4u __attribute__((aligned(4)));   // 4B-aligned float4 load

typedef const __attribute__((address_space(1))) void* gas_t;
typedef __attribute__((address_space(3))) void* las_t;

__device__ __forceinline__ void gload_lds16(const float* g, float* l) {
    __builtin_amdgcn_global_load_lds((gas_t)g, (las_t)l, 16, 0, 0);
}

__global__ __launch_bounds__(NT, 8)
void warp_bicubic_gen(const float* __restrict__ img,
                      const float* __restrict__ dxp,
                      const float* __restrict__ dyp,
                      float* __restrict__ out)
{
    __shared__ float tile[C][TDW];             // 25,344 B -> 2 blocks/CU resident

    int b   = blockIdx.x;
    int swz = (b & 7) * (NB / 8) + (b >> 3);   // XCD-chunked, bijective (1024=8*128)
    int bd  = swz >> 8;                        // displacement batch 0..3
    int ty  = (swz >> 4) & 15;
    int tx  = swz & 15;
    int yb  = ty * TH2;
    int xb  = tx * TW;
    int cb  = min(max(xb - HALO, 0), W - LSTC);   // staged col origin, in-bounds

    int tid  = threadIdx.x;
    int wv   = tid >> 6;                       // 0..15
    int lane = tid & 63;
    int ry   = wv * 2 + (lane >> 5);           // 0..31
    int cidx = lane & 31;
    int y    = yb + ry;
    int x    = xb + cidx;
    int pixoff = y * W + x;

    // ---- 1) dx/dy first (oldest vmem ops: coeff wait leaves staging in flight)
    float dxv = __builtin_nontemporal_load(dxp + bd * HW + pixoff);
    float dyv = __builtin_nontemporal_load(dyp + bd * HW + pixoff);

    // ---- 2) staging: 1 gload_lds16 per wave per plane, shared address math
    if (lane < CPW) {
        int chunk = wv * CPW + lane;           // < 528
        int r  = chunk / CHR;
        int c4 = (chunk - r * CHR) * 4;
        int sr = min(max(yb - HALO + r, 0), H - 1);   // y clamp == ref row clamp
        int soff = sr * W + cb + c4;                  // always in [0, HW-4]
        const float* g0 = img + (size_t)bd * HW + soff;
        float* l0 = &tile[0][chunk * 4];
        gload_lds16(g0,           l0);
        gload_lds16(g0 + 4 * HW,  l0 + TDW);
        gload_lds16(g0 + 8 * HW,  l0 + 2 * TDW);
    }

    // ---- 3) coefficients (one position, reused x3 planes) ----
    float xm = (float)x + dxv;                 // == ref up to ~3e-5 px rounding
    float ym = (float)y + dyv;
    float x0f = floorf(xm), y0f = floorf(ym);
    float ftx = xm - x0f, fty = ym - y0f;
    int x0 = (int)x0f, y0 = (int)y0f;
    int s  = min(max(x0 - 1, 0), W - 4);       // 4-wide window start (image cols)

    float tx2 = ftx * ftx, tx3 = tx2 * ftx;
    float cx0 = (-tx3 + 2.0f * tx2 - ftx) * 0.5f;
    float cx1 = (3.0f * tx3 - 5.0f * tx2 + 2.0f) * 0.5f;
    float cx2 = (-3.0f * tx3 + 4.0f * tx2 + ftx) * 0.5f;
    float cx3 = 1.0f - (cx0 + cx1 + cx2);

    float ty2 = fty * fty, ty3 = ty2 * fty;
    float cy0 = (-ty3 + 2.0f * ty2 - fty) * 0.5f;
    float cy1 = (3.0f * ty3 - 5.0f * ty2 + 2.0f) * 0.5f;
    float cy2 = (-3.0f * ty3 + 4.0f * ty2 + fty) * 0.5f;
    float cy3 = 1.0f - (cy0 + cy1 + cy2);

    float w0, w1, w2, w3;
    if (__builtin_expect(x0 >= 1 && x0 <= W - 3, 1)) {   // interior: weights = cx
        w0 = cx0; w1 = cx1; w2 = cx2; w3 = cx3;
    } else {                                   // fold image-edge taps into window
        w0 = w1 = w2 = w3 = 0.f;
        const float cxa[4] = {cx0, cx1, cx2, cx3};
#pragma unroll
        for (int o = 0; o < 4; ++o) {
            int xi = min(max(x0 - 1 + o, 0), W - 1);
            int e  = xi - s;                   // 0..3 always
            float cc = cxa[o];
            w0 += (e == 0) ? cc : 0.f;
            w1 += (e == 1) ? cc : 0.f;
            w2 += (e == 2) ? cc : 0.f;
            w3 += (e == 3) ? cc : 0.f;
        }
    }

    unsigned rel = (unsigned)(y0 - (yb - HALO + 1));     // staged row of y0-1
    unsigned lsv = (unsigned)(s - cb);                   // staged col of window
    bool intile = (rel <= (unsigned)(RS - 4)) & (lsv <= (unsigned)(LSTC - 4));
    int lbase = (int)rel * LSTC + (int)lsv;

    __syncthreads();   // single barrier: all 3 plane tiles landed

    // ---- 4) stencil: 3 planes, pure LDS + FMA + NT store ----
#pragma unroll
    for (int c = 0; c < C; ++c) {
        int kp = bd + 4 * c;
        const float* __restrict__ tp = &tile[c][0];
        float acc;
        if (__builtin_expect(intile, 1)) {
            const float* rp = tp + lbase;
            float r0 = cy0 * (w0 * rp[0] + w1 * rp[1] + w2 * rp[2] + w3 * rp[3]);
            rp += LSTC;
            float r1 = cy1 * (w0 * rp[0] + w1 * rp[1] + w2 * rp[2] + w3 * rp[3]);
            rp += LSTC;
            float r2 = cy2 * (w0 * rp[0] + w1 * rp[1] + w2 * rp[2] + w3 * rp[3]);
            rp += LSTC;
            float r3 = cy3 * (w0 * rp[0] + w1 * rp[1] + w2 * rp[2] + w3 * rp[3]);
            acc = (r0 + r1) + (r2 + r3);
        } else {
            // rare Gaussian-tail escape: always-correct global path
            const float* __restrict__ plane = img + (size_t)kp * HW;
            const float cya[4] = {cy0, cy1, cy2, cy3};
            acc = 0.f;
#pragma unroll
            for (int j = 0; j < 4; ++j) {
                int yi = min(max(y0 - 1 + j, 0), H - 1);
                f4 v = *(const f4u*)(plane + yi * W + s);
                acc += cya[j] * (w0 * v.x + w1 * v.y + w2 * v.z + w3 * v.w);
            }
        }
        __builtin_nontemporal_store(acc, out + (size_t)kp * HW + pixoff);
    }
}

extern "C" void kernel_launch(void* const* d_in, const int* in_sizes, int n_in,
                              void* d_out, int out_size, void* d_ws, size_t ws_size,
                              hipStream_t stream) {
    const float* img = (const float*)d_in[0];
    const float* dx  = (const float*)d_in[1];
    const float* dy  = (const float*)d_in[2];
    float* out = (float*)d_out;

    dim3 block(NT);
    dim3 grid(NB);   // 1024 blocks, 512 resident -> 2 dispatch generations
    hipLaunchKernelGGL(warp_bicubic_gen, grid, block, 0, stream,
                       img, dx, dy, out);
}